// Round 8
// baseline (780.501 us; speedup 1.0000x reference)
//
#include <hip/hip_runtime.h>

// RFNetwork recurrence (in_in_p dead; P = out_in_p):
//   out_t = (W+P) @ x_t ; P = colrenorm(rowrenorm(P + l*outer(out,x)))
// 16x16 grid, block (r,c) owns 64x64 tile of P_tilde in LDS (one-step-lazy
// column factor f: P_true = Pt * diag(f)).
// TAGGED-DATA exchanges: A publishes per-row (out,R,tag,0) as ONE atomic
// dwordx4; B per-col (colsum,tag) as ONE dwordx2. Consumers read the data
// slots directly until tag==t+1.
// CONGESTION-CONTROLLED polls (round-7 regression fix): fast path = one full
// read; on miss, tag-only spin (4B/slot) with s_sleep backoff, then one full
// re-read. Slot stable after tag match (rewrite is 2-step-gated, below).
// Overwrite safety (parity dbuf, skew): publish A(t) can only overwrite the
// slot row-mates read at poll A(t-2): gated by row-mates flagA >= t-1
// (flagA=s+1 set after ALL threads finish poll A(s), barrier-covered).
// Publish B(t) likewise gated by col-mates flagB >= t-1. 2-step-stale ->
// first-try hits; off the critical path.
// Latency hiding: pass1 writes pf=Pt*f back in place (pass2 pre-scale);
// W.x partial for t+1 computed between publish B and poll B.
// All reduction trees fixed -> bit-deterministic. No data atomics.

typedef float f32x4 __attribute__((ext_vector_type(4)));
typedef float f32x2 __attribute__((ext_vector_type(2)));

#define T_STEPS 128
#define N 1024
#define GR 16
#define GC 16
#define TB 64
#define NT 256
#define LMBDA 0.01f

__global__ __launch_bounds__(NT) void rf2d_kernel(
    const float* __restrict__ X,    // [T][N]
    const float* __restrict__ W,    // [N][N]
    float* __restrict__ OUT,        // [T][N]
    f32x4* __restrict__ OutA,       // [2][GC][N] tagged (out,R,tag,pad)
    f32x2* __restrict__ ScolB,      // [2][GR][N] tagged (colsum,tag)
    unsigned* __restrict__ fAr,     // [GR][GC] flagA, row-major
    unsigned* __restrict__ fBc) {   // [GC][GR] flagB, col-major
  __shared__ float Pl[TB * TB];     // 16 KB tile, f32x4-chunk XOR swizzle
  __shared__ float f_loc[TB];
  __shared__ float rfl[TB], rol_l[TB];
  __shared__ float SLc[4][TB];
  __shared__ float SLd[4][TB];
  __shared__ float sxAll[T_STEPS];

  const int tid = threadIdx.x;
  const int b = blockIdx.x;
  const int r = b >> 4, c = b & 15;
  const int grow = r * TB, gcol = c * TB;
  const int r_loc = tid >> 2, q = tid & 3;   // pass1: 4 lanes per row
  const int c_loc = tid & 63, rg = tid >> 6; // pass2: column slice

  // ---- init ----
  for (int i = tid; i < TB * TB; i += NT) Pl[i] = 0.f;
  if (tid < TB) f_loc[tid] = 1.f;
  if (tid < T_STEPS) {  // sx[t] precompute (X is a fixed input)
    const f32x4* X4i = (const f32x4*)(X + (size_t)tid * N);
    f32x4 acc = {0.f, 0.f, 0.f, 0.f};
    for (int j = 0; j < N / 4; ++j) acc += X4i[j];
    sxAll[tid] = (acc.x + acc.y) + (acc.z + acc.w);
  }
  f32x4 wr[4];
#pragma unroll
  for (int k = 0; k < 4; ++k)
    wr[k] = *(const f32x4*)(W + (size_t)(grow + r_loc) * N + gcol + 16 * q + 4 * k);

  // W.x partial for t=0
  float wrx = 0.f;
  {
    const f32x4* Xn = (const f32x4*)(X + gcol);
#pragma unroll
    for (int k = 0; k < 4; ++k) {
      f32x4 xv = Xn[4 * q + k];
      wrx += (wr[k].x * xv.x + wr[k].y * xv.y) + (wr[k].z * xv.z + wr[k].w * xv.w);
    }
  }
  __syncthreads();

  for (int t = 0; t < T_STEPS; ++t) {
    const int p = t & 1;
    const unsigned tg = t + 1u;
    const float tagf = __uint_as_float(tg);

    // ---- pass1 + in-place prescale (Pl <- Pt*f) ----
    float a_out = wrx, a_R = 0.f;
    {
      f32x4* PlV = (f32x4*)Pl;
      const f32x4* FV = (const f32x4*)f_loc;
      const f32x4* XV = (const f32x4*)(X + (size_t)t * N + gcol);
#pragma unroll
      for (int k = 0; k < 4; ++k) {
        const int lc = 4 * q + k;
        const int slot = r_loc * 16 + (lc ^ (r_loc & 15));
        f32x4 pv = PlV[slot];
        f32x4 fv = FV[lc];
        f32x4 xv = XV[lc];
        f32x4 pf = pv * fv;
        PlV[slot] = pf;  // prescaled for pass2 (same thread's elements only)
        a_R += (pf.x + pf.y) + (pf.z + pf.w);
        a_out += (pf.x * xv.x + pf.y * xv.y) + (pf.z * xv.z + pf.w * xv.w);
      }
    }
    a_out += __shfl_xor(a_out, 1, 64); a_out += __shfl_xor(a_out, 2, 64);
    a_R   += __shfl_xor(a_R, 1, 64);   a_R   += __shfl_xor(a_R, 2, 64);

    // ---- publish A: one atomic 16B tagged store per row ----
    if (q == 0) {
      f32x4 v; v.x = a_out; v.y = a_R; v.z = tagf; v.w = 0.f;
      f32x4* dst = OutA + (size_t)p * GC * N + (size_t)c * N + grow + r_loc;
      asm volatile("global_store_dwordx4 %0, %1, off sc0 sc1"
                   :: "v"(dst), "v"(v) : "memory");
    }

    // ---- data-poll A: fast full read, tag-only backoff spin on miss ----
    f32x4 v0, v1, v2, v3;
    {
      const f32x4* baseA = OutA + (size_t)p * GC * N + grow + r_loc;
      const f32x4* a0 = baseA + (size_t)(4 * q + 0) * N;
      const f32x4* a1 = baseA + (size_t)(4 * q + 1) * N;
      const f32x4* a2 = baseA + (size_t)(4 * q + 2) * N;
      const f32x4* a3 = baseA + (size_t)(4 * q + 3) * N;
      asm volatile("global_load_dwordx4 %0, %4, off sc0 sc1\n\t"
                   "global_load_dwordx4 %1, %5, off sc0 sc1\n\t"
                   "global_load_dwordx4 %2, %6, off sc0 sc1\n\t"
                   "global_load_dwordx4 %3, %7, off sc0 sc1\n\t"
                   "s_waitcnt vmcnt(0)"
                   : "=v"(v0), "=v"(v1), "=v"(v2), "=v"(v3)
                   : "v"(a0), "v"(a1), "v"(a2), "v"(a3)
                   : "memory");
      __builtin_amdgcn_sched_barrier(0);
      if (!(__float_as_uint(v0.z) == tg && __float_as_uint(v1.z) == tg &&
            __float_as_uint(v2.z) == tg && __float_as_uint(v3.z) == tg)) {
        const unsigned* t0 = (const unsigned*)a0 + 2;  // .z word
        const unsigned* t1 = (const unsigned*)a1 + 2;
        const unsigned* t2 = (const unsigned*)a2 + 2;
        const unsigned* t3 = (const unsigned*)a3 + 2;
        unsigned w0, w1, w2, w3;
        do {
          __builtin_amdgcn_s_sleep(2);
          asm volatile("global_load_dword %0, %4, off sc0 sc1\n\t"
                       "global_load_dword %1, %5, off sc0 sc1\n\t"
                       "global_load_dword %2, %6, off sc0 sc1\n\t"
                       "global_load_dword %3, %7, off sc0 sc1\n\t"
                       "s_waitcnt vmcnt(0)"
                       : "=v"(w0), "=v"(w1), "=v"(w2), "=v"(w3)
                       : "v"(t0), "v"(t1), "v"(t2), "v"(t3)
                       : "memory");
          __builtin_amdgcn_sched_barrier(0);
        } while (!(w0 == tg && w1 == tg && w2 == tg && w3 == tg));
        // slot stable after tag match (rewrite 2-step-gated) -> one re-read
        asm volatile("global_load_dwordx4 %0, %4, off sc0 sc1\n\t"
                     "global_load_dwordx4 %1, %5, off sc0 sc1\n\t"
                     "global_load_dwordx4 %2, %6, off sc0 sc1\n\t"
                     "global_load_dwordx4 %3, %7, off sc0 sc1\n\t"
                     "s_waitcnt vmcnt(0)"
                     : "=v"(v0), "=v"(v1), "=v"(v2), "=v"(v3)
                     : "v"(a0), "v"(a1), "v"(a2), "v"(a3)
                     : "memory");
        __builtin_amdgcn_sched_barrier(0);
      }
    }
    {
      float po = (v0.x + v1.x) + (v2.x + v3.x);
      float pR = (v0.y + v1.y) + (v2.y + v3.y);
      po += __shfl_xor(po, 1, 64); po += __shfl_xor(po, 2, 64);
      pR += __shfl_xor(pR, 1, 64); pR += __shfl_xor(pR, 2, 64);
      float ol = LMBDA * po;
      float R1 = pR + ol * sxAll[t];
      float rf = (R1 > 1.f) ? 1.f / R1 : 1.f;  // MAX_POST = 1
      if (q == 0) { rfl[r_loc] = rf; rol_l[r_loc] = rf * ol; }
      if (c == 0 && q == 0) OUT[(size_t)t * N + grow + r_loc] = po;
    }
    if (t == T_STEPS - 1) break;  // state past last output is dead work
    __syncthreads();  // (b) rfl/rol_l + prescaled Pl visible; all polled A

    if (tid == 0)  // flagA: this block finished poll A(t)
      __hip_atomic_store(&fAr[r * GC + c], tg, __ATOMIC_RELAXED, __HIP_MEMORY_SCOPE_AGENT);

    // ---- pass2: v = rf*pf + rol*x column-wise; tile colsum partials ----
    {
      const float xc = X[(size_t)t * N + gcol + c_loc];
      float cacc = 0.f;
#pragma unroll
      for (int rr = 0; rr < 16; ++rr) {
        const int row = rg * 16 + rr;
        const int idx = row * 64 + ((((c_loc >> 2) ^ (row & 15))) << 2) + (c_loc & 3);
        float v = rfl[row] * Pl[idx] + rol_l[row] * xc;
        Pl[idx] = v;
        cacc += v;
      }
      SLc[rg][c_loc] = cacc;
    }
    // cond-2 (gates publish B(t)): col-mates' flagB >= t-1 (2 steps stale)
    if (tid < 16 && (int)t >= 2) {
      const unsigned tgt = t - 1u;
      while (__hip_atomic_load(&fBc[c * GR + tid], __ATOMIC_RELAXED,
                               __HIP_MEMORY_SCOPE_AGENT) < tgt)
        __builtin_amdgcn_s_sleep(2);
    }
    __syncthreads();  // (c)

    // ---- publish B: one atomic 8B tagged store per column ----
    if (tid < TB) {
      float scol = (SLc[0][tid] + SLc[1][tid]) + (SLc[2][tid] + SLc[3][tid]);
      f32x2 v; v.x = scol; v.y = tagf;
      f32x2* dst = ScolB + (size_t)p * GR * N + (size_t)r * N + gcol + tid;
      asm volatile("global_store_dwordx2 %0, %1, off sc0 sc1"
                   :: "v"(dst), "v"(v) : "memory");
    }

    // ---- hidden under B-wait: W.x partial for step t+1 ----
    wrx = 0.f;
    {
      const f32x4* Xn = (const f32x4*)(X + (size_t)(t + 1) * N + gcol);
#pragma unroll
      for (int k = 0; k < 4; ++k) {
        f32x4 xv = Xn[4 * q + k];
        wrx += (wr[k].x * xv.x + wr[k].y * xv.y) + (wr[k].z * xv.z + wr[k].w * xv.w);
      }
    }

    // ---- data-poll B: fast full read, tag-only backoff spin on miss ----
    {
      f32x2 u0, u1, u2, u3;
      const f32x2* baseB = ScolB + (size_t)p * GR * N + gcol + c_loc;
      const f32x2* b0 = baseB + (size_t)(4 * rg + 0) * N;
      const f32x2* b1 = baseB + (size_t)(4 * rg + 1) * N;
      const f32x2* b2 = baseB + (size_t)(4 * rg + 2) * N;
      const f32x2* b3 = baseB + (size_t)(4 * rg + 3) * N;
      asm volatile("global_load_dwordx2 %0, %4, off sc0 sc1\n\t"
                   "global_load_dwordx2 %1, %5, off sc0 sc1\n\t"
                   "global_load_dwordx2 %2, %6, off sc0 sc1\n\t"
                   "global_load_dwordx2 %3, %7, off sc0 sc1\n\t"
                   "s_waitcnt vmcnt(0)"
                   : "=v"(u0), "=v"(u1), "=v"(u2), "=v"(u3)
                   : "v"(b0), "v"(b1), "v"(b2), "v"(b3)
                   : "memory");
      __builtin_amdgcn_sched_barrier(0);
      if (!(__float_as_uint(u0.y) == tg && __float_as_uint(u1.y) == tg &&
            __float_as_uint(u2.y) == tg && __float_as_uint(u3.y) == tg)) {
        const unsigned* t0 = (const unsigned*)b0 + 1;  // .y word
        const unsigned* t1 = (const unsigned*)b1 + 1;
        const unsigned* t2 = (const unsigned*)b2 + 1;
        const unsigned* t3 = (const unsigned*)b3 + 1;
        unsigned w0, w1, w2, w3;
        do {
          __builtin_amdgcn_s_sleep(2);
          asm volatile("global_load_dword %0, %4, off sc0 sc1\n\t"
                       "global_load_dword %1, %5, off sc0 sc1\n\t"
                       "global_load_dword %2, %6, off sc0 sc1\n\t"
                       "global_load_dword %3, %7, off sc0 sc1\n\t"
                       "s_waitcnt vmcnt(0)"
                       : "=v"(w0), "=v"(w1), "=v"(w2), "=v"(w3)
                       : "v"(t0), "v"(t1), "v"(t2), "v"(t3)
                       : "memory");
          __builtin_amdgcn_sched_barrier(0);
        } while (!(w0 == tg && w1 == tg && w2 == tg && w3 == tg));
        asm volatile("global_load_dwordx2 %0, %4, off sc0 sc1\n\t"
                     "global_load_dwordx2 %1, %5, off sc0 sc1\n\t"
                     "global_load_dwordx2 %2, %6, off sc0 sc1\n\t"
                     "global_load_dwordx2 %3, %7, off sc0 sc1\n\t"
                     "s_waitcnt vmcnt(0)"
                     : "=v"(u0), "=v"(u1), "=v"(u2), "=v"(u3)
                     : "v"(b0), "v"(b1), "v"(b2), "v"(b3)
                     : "memory");
        __builtin_amdgcn_sched_barrier(0);
      }
      SLd[rg][c_loc] = (u0.x + u1.x) + (u2.x + u3.x);
    }
    __syncthreads();  // (d) all polled B; SLd visible

    if (tid == 0)  // flagB: this block finished poll B(t)
      __hip_atomic_store(&fBc[c * GR + r], tg, __ATOMIC_RELAXED, __HIP_MEMORY_SCOPE_AGENT);
    if (tid < TB) {
      float s = (SLd[0][tid] + SLd[1][tid]) + (SLd[2][tid] + SLd[3][tid]);
      f_loc[tid] = (s > 1.f) ? 1.f / s : 1.f;  // MAX_PRE = 1
    }
    // cond-1 (gates publish A(t+1)): row-mates' flagA >= t (2 steps stale)
    if (tid >= 16 && tid < 32 && t >= 1) {
      const unsigned tgt = t;
      while (__hip_atomic_load(&fAr[r * GC + (tid - 16)], __ATOMIC_RELAXED,
                               __HIP_MEMORY_SCOPE_AGENT) < tgt)
        __builtin_amdgcn_s_sleep(2);
    }
    __syncthreads();  // (e) f_loc visible; cond-1 done
  }
}

extern "C" void kernel_launch(void* const* d_in, const int* in_sizes, int n_in,
                              void* d_out, int out_size, void* d_ws, size_t ws_size,
                              hipStream_t stream) {
  const float* X = (const float*)d_in[0];   // inputs [128][1024]
  const float* W = (const float*)d_in[2];   // out_in_fixed [1024][1024]
  float* OUT = (float*)d_out;               // [128][1024] f32

  char* ws = (char*)d_ws;
  // layout: fAr (1KB) | fBc (1KB) | pad to 4KB | OutA (512KB) | ScolB (256KB)
  unsigned* fAr = (unsigned*)ws;
  unsigned* fBc = (unsigned*)(ws + 1024);
  f32x4* OutA = (f32x4*)(ws + 4096);
  f32x2* ScolB = (f32x2*)(ws + 4096 + (size_t)2 * GC * N * sizeof(f32x4));

  // Only the flags need clearing each launch (monotone within a launch).
  // Tagged data buffers self-validate: stale tags never match their target.
  hipMemsetAsync(ws, 0, 2048, stream);

  hipLaunchKernelGGL(rf2d_kernel, dim3(GR * GC), dim3(NT), 0, stream,
                     X, W, OUT, OutA, ScolB, fAr, fBc);
}

// Round 9
// 632.018 us; speedup vs baseline: 1.2349x; 1.2349x over previous
//
#include <hip/hip_runtime.h>

// RFNetwork recurrence (in_in_p dead; P = out_in_p):
//   out_t = (W+P) @ x_t ; P = colrenorm(rowrenorm(P + l*outer(out,x)))
// 16x16 grid, block (r,c) owns 64x64 tile of P_tilde in LDS (one-step-lazy
// column factor f: P_true = Pt * diag(f)).
// Round-6 flag-broadcast structure (sparse polling: few threads / few LINES)
// + refinements:
//  - consumers poll the PRODUCER FLAG LINE (dwordx4 of 4 needed flags) per
//    thread, then immediately load their own data chunks -> no post-poll
//    barrier, AND-radix 4 instead of 31.
//  - safety halves of the polls (row/col transitive overwrite gating) moved
//    off the critical path: pollA-col before publish B, pollB-row before
//    publish A(t+1). Same proof as round 6: publish A(t+2) overwriting the
//    parity-p slot is preceded by pollB(t+1) seeing row-mates' fB>=t+2,
//    which they set only after finishing their A(t+1) reads (a fortiori
//    A(t)); symmetrically for Scol via fAc.
//  - pass1 prescales Pt*f in place (pass2 drops the f multiply).
//  - W.x partial for t+1 computed between flag-B store and poll B.
// All reduction trees fixed -> bit-deterministic. No data atomics.

typedef float f32x4 __attribute__((ext_vector_type(4)));
typedef float f32x2 __attribute__((ext_vector_type(2)));
typedef unsigned u32x4 __attribute__((ext_vector_type(4)));

#define T_STEPS 128
#define N 1024
#define GR 16
#define GC 16
#define TB 64
#define NT 256
#define LMBDA 0.01f

__global__ __launch_bounds__(NT) void rf2d_kernel(
    const float* __restrict__ X,    // [T][N]
    const float* __restrict__ W,    // [N][N]
    float* __restrict__ OUT,        // [T][N]
    f32x2* __restrict__ OutP,       // [2][GC][N] (out,R) partials
    float* __restrict__ Scol,       // [2][GR][N] colsum partials
    unsigned* __restrict__ fAr,     // [GR][GC] A-publish flags, row-major
    unsigned* __restrict__ fAc,     // [GC][GR] A-publish flags, col-major
    unsigned* __restrict__ fBc,     // [GC][GR] B-publish flags, col-major
    unsigned* __restrict__ fBr) {   // [GR][GC] B-publish flags, row-major
  __shared__ float Pl[TB * TB];     // 16 KB tile, f32x4-chunk XOR swizzle
  __shared__ float f_loc[TB];
  __shared__ float rfl[TB], rol_l[TB];
  __shared__ float SLc[4][TB];
  __shared__ float SLd[4][TB];
  __shared__ float sxAll[T_STEPS];

  const int tid = threadIdx.x;
  const int b = blockIdx.x;
  const int r = b >> 4, c = b & 15;
  const int grow = r * TB, gcol = c * TB;
  const int r_loc = tid >> 2, q = tid & 3;   // pass1: 4 lanes per row
  const int c_loc = tid & 63, rg = tid >> 6; // pass2: column slice

  // ---- init ----
  for (int i = tid; i < TB * TB; i += NT) Pl[i] = 0.f;
  if (tid < TB) f_loc[tid] = 1.f;
  {  // sx[t] for all steps (X fixed): 2 threads per row, fixed combine order
    const int rowi = tid >> 1, half = tid & 1;
    const f32x4* Xr = (const f32x4*)(X + (size_t)rowi * N) + half * 128;
    f32x4 acc = {0.f, 0.f, 0.f, 0.f};
    for (int j = 0; j < 128; ++j) acc += Xr[j];
    ((float*)SLc)[tid] = (acc.x + acc.y) + (acc.z + acc.w);
  }
  __syncthreads();
  if (tid < T_STEPS)
    sxAll[tid] = ((float*)SLc)[2 * tid] + ((float*)SLc)[2 * tid + 1];

  f32x4 wr[4];
#pragma unroll
  for (int k = 0; k < 4; ++k)
    wr[k] = *(const f32x4*)(W + (size_t)(grow + r_loc) * N + gcol + 16 * q + 4 * k);

  // W.x partial for t=0
  float wrx = 0.f;
  {
    const f32x4* Xn = (const f32x4*)(X + gcol);
#pragma unroll
    for (int k = 0; k < 4; ++k) {
      f32x4 xv = Xn[4 * q + k];
      wrx += (wr[k].x * xv.x + wr[k].y * xv.y) + (wr[k].z * xv.z + wr[k].w * xv.w);
    }
  }
  __syncthreads();

  for (int t = 0; t < T_STEPS; ++t) {
    const int p = t & 1;
    const unsigned tg = t + 1u;

    // ---- pass1 + in-place prescale (Pl <- Pt*f) ----
    float a_out = wrx, a_R = 0.f;
    {
      f32x4* PlV = (f32x4*)Pl;
      const f32x4* FV = (const f32x4*)f_loc;
      const f32x4* XV = (const f32x4*)(X + (size_t)t * N + gcol);
#pragma unroll
      for (int k = 0; k < 4; ++k) {
        const int lc = 4 * q + k;
        const int slot = r_loc * 16 + (lc ^ (r_loc & 15));
        f32x4 pv = PlV[slot];
        f32x4 fv = FV[lc];
        f32x4 xv = XV[lc];
        f32x4 pf = pv * fv;
        PlV[slot] = pf;  // prescaled for pass2 (same thread's elements only)
        a_R += (pf.x + pf.y) + (pf.z + pf.w);
        a_out += (pf.x * xv.x + pf.y * xv.y) + (pf.z * xv.z + pf.w * xv.w);
      }
    }
    a_out += __shfl_xor(a_out, 1, 64); a_out += __shfl_xor(a_out, 2, 64);
    a_R   += __shfl_xor(a_R, 1, 64);   a_R   += __shfl_xor(a_R, 2, 64);

    // ---- publish A: (out,R) f32x2 per row ----
    if (q == 0) {
      f32x2 v; v.x = a_out; v.y = a_R;
      f32x2* dst = OutP + (size_t)p * GC * N + (size_t)c * N + grow + r_loc;
      asm volatile("global_store_dwordx2 %0, %1, off sc0 sc1"
                   :: "v"(dst), "v"(v) : "memory");
    }
    __syncthreads();  // drain-A: all waves' stores at LLC (vmcnt(0) pre-barrier)
    if (tid == 0) {
      __hip_atomic_store(&fAr[r * GC + c], tg, __ATOMIC_RELAXED, __HIP_MEMORY_SCOPE_AGENT);
      __hip_atomic_store(&fAc[c * GR + r], tg, __ATOMIC_RELAXED, __HIP_MEMORY_SCOPE_AGENT);
    }

    // ---- per-thread poll of own 4 producer flags (one dwordx4, 1 line) ----
    {
      const unsigned* fp = fAr + r * GC + 4 * q;
      u32x4 fv;
      for (;;) {
        asm volatile("global_load_dwordx4 %0, %1, off sc0 sc1\n\ts_waitcnt vmcnt(0)"
                     : "=v"(fv) : "v"(fp) : "memory");
        __builtin_amdgcn_sched_barrier(0);
        if (fv.x >= tg && fv.y >= tg && fv.z >= tg && fv.w >= tg) break;
        __builtin_amdgcn_s_sleep(1);
      }
    }
    // ---- read own 4 chunks, reduce ----
    {
      f32x2 v0, v1, v2, v3;
      const f32x2* baseA = OutP + (size_t)p * GC * N + grow + r_loc;
      asm volatile("global_load_dwordx2 %0, %4, off sc0 sc1\n\t"
                   "global_load_dwordx2 %1, %5, off sc0 sc1\n\t"
                   "global_load_dwordx2 %2, %6, off sc0 sc1\n\t"
                   "global_load_dwordx2 %3, %7, off sc0 sc1\n\t"
                   "s_waitcnt vmcnt(0)"
                   : "=v"(v0), "=v"(v1), "=v"(v2), "=v"(v3)
                   : "v"(baseA + (size_t)(4 * q + 0) * N),
                     "v"(baseA + (size_t)(4 * q + 1) * N),
                     "v"(baseA + (size_t)(4 * q + 2) * N),
                     "v"(baseA + (size_t)(4 * q + 3) * N)
                   : "memory");
      __builtin_amdgcn_sched_barrier(0);
      float po = (v0.x + v1.x) + (v2.x + v3.x);
      float pR = (v0.y + v1.y) + (v2.y + v3.y);
      po += __shfl_xor(po, 1, 64); po += __shfl_xor(po, 2, 64);
      pR += __shfl_xor(pR, 1, 64); pR += __shfl_xor(pR, 2, 64);
      float ol = LMBDA * po;
      float R1 = pR + ol * sxAll[t];
      float rf = (R1 > 1.f) ? 1.f / R1 : 1.f;  // MAX_POST = 1
      if (q == 0) { rfl[r_loc] = rf; rol_l[r_loc] = rf * ol; }
      if (c == 0 && q == 0) OUT[(size_t)t * N + grow + r_loc] = po;
    }
    if (t == T_STEPS - 1) break;  // state past last output is dead work
    __syncthreads();  // (b) rfl/rol_l + prescaled Pl visible

    // ---- pass2: v = rf*pf + rol*x column-wise; tile colsum partials ----
    {
      const float xc = X[(size_t)t * N + gcol + c_loc];
      float cacc = 0.f;
#pragma unroll
      for (int rr = 0; rr < 16; ++rr) {
        const int row = rg * 16 + rr;
        const int idx = row * 64 + ((((c_loc >> 2) ^ (row & 15))) << 2) + (c_loc & 3);
        float v = rfl[row] * Pl[idx] + rol_l[row] * xc;
        Pl[idx] = v;
        cacc += v;
      }
      SLc[rg][c_loc] = cacc;
    }
    // safety pollA-col (gates publish B(t)): col-mates published A(t) ->
    // they will not re-touch Scol[p] readers... (transitive proof, header)
    if (tid < 16) {
      while (__hip_atomic_load(&fAc[c * GR + tid], __ATOMIC_RELAXED,
                               __HIP_MEMORY_SCOPE_AGENT) < tg)
        __builtin_amdgcn_s_sleep(1);
    }
    __syncthreads();  // (c) SLc visible; safety poll done

    // ---- publish B: colsum float per column ----
    if (tid < TB) {
      float scol = (SLc[0][tid] + SLc[1][tid]) + (SLc[2][tid] + SLc[3][tid]);
      float* dst = Scol + (size_t)p * GR * N + (size_t)r * N + gcol + tid;
      asm volatile("global_store_dword %0, %1, off sc0 sc1"
                   :: "v"(dst), "v"(scol) : "memory");
    }
    __syncthreads();  // drain-B
    if (tid == 0) {
      __hip_atomic_store(&fBc[c * GR + r], tg, __ATOMIC_RELAXED, __HIP_MEMORY_SCOPE_AGENT);
      __hip_atomic_store(&fBr[r * GC + c], tg, __ATOMIC_RELAXED, __HIP_MEMORY_SCOPE_AGENT);
    }

    // ---- hidden under B-wait: W.x partial for step t+1 ----
    wrx = 0.f;
    {
      const f32x4* Xn = (const f32x4*)(X + (size_t)(t + 1) * N + gcol);
#pragma unroll
      for (int k = 0; k < 4; ++k) {
        f32x4 xv = Xn[4 * q + k];
        wrx += (wr[k].x * xv.x + wr[k].y * xv.y) + (wr[k].z * xv.z + wr[k].w * xv.w);
      }
    }

    // ---- per-thread poll of own 4 B-producer flags (one dwordx4) ----
    {
      const unsigned* fp = fBc + c * GR + 4 * rg;
      u32x4 fv;
      for (;;) {
        asm volatile("global_load_dwordx4 %0, %1, off sc0 sc1\n\ts_waitcnt vmcnt(0)"
                     : "=v"(fv) : "v"(fp) : "memory");
        __builtin_amdgcn_sched_barrier(0);
        if (fv.x >= tg && fv.y >= tg && fv.z >= tg && fv.w >= tg) break;
        __builtin_amdgcn_s_sleep(1);
      }
    }
    // ---- read own 4 colsum chunks ----
    {
      float u0, u1, u2, u3;
      const float* baseB = Scol + (size_t)p * GR * N + gcol + c_loc;
      asm volatile("global_load_dword %0, %4, off sc0 sc1\n\t"
                   "global_load_dword %1, %5, off sc0 sc1\n\t"
                   "global_load_dword %2, %6, off sc0 sc1\n\t"
                   "global_load_dword %3, %7, off sc0 sc1\n\t"
                   "s_waitcnt vmcnt(0)"
                   : "=v"(u0), "=v"(u1), "=v"(u2), "=v"(u3)
                   : "v"(baseB + (size_t)(4 * rg + 0) * N),
                     "v"(baseB + (size_t)(4 * rg + 1) * N),
                     "v"(baseB + (size_t)(4 * rg + 2) * N),
                     "v"(baseB + (size_t)(4 * rg + 3) * N)
                   : "memory");
      __builtin_amdgcn_sched_barrier(0);
      SLd[rg][c_loc] = (u0 + u1) + (u2 + u3);
    }
    // safety pollB-row (gates publish A(t+1)): done before sync (e)
    if (tid >= 16 && tid < 32) {
      while (__hip_atomic_load(&fBr[r * GC + (tid - 16)], __ATOMIC_RELAXED,
                               __HIP_MEMORY_SCOPE_AGENT) < tg)
        __builtin_amdgcn_s_sleep(1);
    }
    __syncthreads();  // (d) SLd visible; safety poll done
    if (tid < TB) {
      float s = (SLd[0][tid] + SLd[1][tid]) + (SLd[2][tid] + SLd[3][tid]);
      f_loc[tid] = (s > 1.f) ? 1.f / s : 1.f;  // MAX_PRE = 1
    }
    __syncthreads();  // (e) f_loc visible
  }
}

extern "C" void kernel_launch(void* const* d_in, const int* in_sizes, int n_in,
                              void* d_out, int out_size, void* d_ws, size_t ws_size,
                              hipStream_t stream) {
  const float* X = (const float*)d_in[0];   // inputs [128][1024]
  const float* W = (const float*)d_in[2];   // out_in_fixed [1024][1024]
  float* OUT = (float*)d_out;               // [128][1024] f32

  char* ws = (char*)d_ws;
  // layout: fAr|fAc|fBc|fBr (1KB each, memset) | OutP 256KB | Scol 128KB
  unsigned* fAr = (unsigned*)ws;
  unsigned* fAc = (unsigned*)(ws + 1024);
  unsigned* fBc = (unsigned*)(ws + 2048);
  unsigned* fBr = (unsigned*)(ws + 3072);
  f32x2* OutP = (f32x2*)(ws + 4096);
  float* Scol = (float*)(ws + 4096 + (size_t)2 * GC * N * sizeof(f32x2));

  // flags zero at every (graph-replayed) launch; monotone within a launch.
  // Data buffers need no clear: every read is flag-gated.
  hipMemsetAsync(ws, 0, 4096, stream);

  hipLaunchKernelGGL(rf2d_kernel, dim3(GR * GC), dim3(NT), 0, stream,
                     X, W, OUT, OutP, Scol, fAr, fAc, fBc, fBr);
}